// Round 13
// baseline (4030.942 us; speedup 1.0000x reference)
//
#include <hip/hip_runtime.h>

typedef unsigned int u32;
typedef unsigned short u16;
typedef short bf16x8 __attribute__((ext_vector_type(8)));
typedef float f32x4 __attribute__((ext_vector_type(4)));

#define TLEN 1000
#define BATCH 128
#define IDIM 64
#define HDIM 512

#define NWG 256
#define NTHR 256

// ws byte offsets (pack offsets unchanged)
#define H0_OFF 0
#define H1_OFF 262144
#define PX0_OFF 525312
#define PH0_OFF 721920
#define PX1_OFF 2294784
#define PH1_OFF 3867648
#define FLG_OFF 5440512
#define XSL_OFF 5442560

__device__ __forceinline__ u16 f2bf(float f) {
  u32 u = __float_as_uint(f);
  u += 0x7fffu + ((u >> 16) & 1u);
  return (u16)(u >> 16);
}
__device__ __forceinline__ float bf2f(u16 h) { return __uint_as_float(((u32)h) << 16); }
__device__ __forceinline__ float sigm(float x) { return 1.0f / (1.0f + __expf(-x)); }
__device__ __forceinline__ float tanhfast(float x) {
  float e = __expf(-2.0f * fabsf(x));
  float t = (1.0f - e) / (1.0f + e);
  return x >= 0.0f ? t : -t;
}
__device__ __forceinline__ u32 umin2(u32 a, u32 b) { return a < b ? a : b; }
__device__ __forceinline__ u32 umax2(u32 a, u32 b) { return a > b ? a : b; }

// ---- system scope (sc0 sc1): r6-r11 proven for flags + cross-cluster data ----
__device__ __forceinline__ void sys_st16(u16* p, u32 v) {
  asm volatile("global_store_short %0, %1, off sc0 sc1" ::"v"(p), "v"(v) : "memory");
}
__device__ __forceinline__ void sys_st32(u32* p, u32 v) {
  asm volatile("global_store_dword %0, %1, off sc0 sc1" ::"v"(p), "v"(v) : "memory");
}
__device__ __forceinline__ uint4 sys_ld128(const u32* p) {
  uint4 v;
  asm volatile("global_load_dwordx4 %0, %1, off sc0 sc1\n\ts_waitcnt vmcnt(0)"
               : "=v"(v) : "v"(p) : "memory");
  return v;
}
__device__ __forceinline__ void sys_ldA(bf16x8& d, const u16* p) {
  asm volatile("global_load_dwordx4 %0, %1, off sc0 sc1" : "=v"(d) : "v"(p));
}
// ---- device scope (sc1 only): coherence point = LLC; probed redundantly ----
__device__ __forceinline__ void dev_st32(u32* p, u32 v) {
  asm volatile("global_store_dword %0, %1, off sc1" ::"v"(p), "v"(v) : "memory");
}
__device__ __forceinline__ uint4 dev_ld128(const u32* p) {
  uint4 v;
  asm volatile("global_load_dwordx4 %0, %1, off sc1\n\ts_waitcnt vmcnt(0)"
               : "=v"(v) : "v"(p) : "memory");
  return v;
}
// ---- sc0 (SE-scope) ops: DATA ONLY (r11-proven under a proven barrier).
//      NEVER for flags: SE scope is narrower than XCD -> polling deadlock (r10/r12).
__device__ __forceinline__ void l2_st16(u16* p, u32 v) {
  asm volatile("global_store_short %0, %1, off sc0" ::"v"(p), "v"(v) : "memory");
}
__device__ __forceinline__ void l2_ldA(bf16x8& d, const u16* p) {
  asm volatile("global_load_dwordx4 %0, %1, off sc0" : "=v"(d) : "v"(p));
}

// ---------------- weight pre-pack into MFMA B-fragment order (unchanged) ------
__global__ void pack_weights(const float* Wih0, const float* Whh0,
                             const float* Wih1, const float* Whh1, char* ws) {
  int fid = blockIdx.x * NTHR + threadIdx.x;
  const float* src;
  int K, Kks;
  size_t obase;
  int f = fid;
  if (f < 12288) {
    src = Wih0; K = 64; Kks = 2; obase = PX0_OFF;
  } else if (f < 12288 + 98304) {
    f -= 12288; src = Whh0; K = 512; Kks = 16; obase = PH0_OFF;
  } else if (f < 12288 + 2 * 98304) {
    f -= 12288 + 98304; src = Wih1; K = 512; Kks = 16; obase = PX1_OFF;
  } else if (f < 12288 + 3 * 98304) {
    f -= 12288 + 2 * 98304; src = Whh1; K = 512; Kks = 16; obase = PH1_OFF;
  } else {
    return;
  }
  int lane = f & 63;
  int r = f >> 6;
  int ks = r % Kks; r /= Kks;
  int ct = r % 3;
  int sl = r / 3;
  int grow = ct * 512 + sl * 16 + (lane & 15);
  int k = ks * 32 + ((lane >> 4) * 8);
  const float* s = src + (size_t)grow * K + k;
  u32 p0 = f2bf(s[0]) | ((u32)f2bf(s[1]) << 16);
  u32 p1 = f2bf(s[2]) | ((u32)f2bf(s[3]) << 16);
  u32 p2 = f2bf(s[4]) | ((u32)f2bf(s[5]) << 16);
  u32 p3 = f2bf(s[6]) | ((u32)f2bf(s[7]) << 16);
  *(uint4*)(ws + obase + (size_t)f * 16) = make_uint4(p0, p1, p2, p3);
}

// ---- barrier: dual-scope release (sc1 + sc0sc1), dual-array poll.
//      Hang-proof: the sc0sc1 copy alone is the r6-r11 proven mechanism. ----
__device__ __forceinline__ void fast_barrier(u32* flagsS, u32* flagsD, int fidx, u32 target) {
  __syncthreads();  // per-wave vmcnt(0) drain before s_barrier (compiler)
  if (threadIdx.x == 0) {
    asm volatile("s_waitcnt vmcnt(0)" ::: "memory");
    dev_st32(flagsD + fidx, target);   // device scope (LLC coherence point)
    sys_st32(flagsS + fidx, target);   // system scope (proven fallback)
  }
  if (threadIdx.x < 64) {
    const int lane = threadIdx.x;
    for (;;) {
      u32 m = 0xFFFFFFFFu;
      if (lane < 8) {
        uint4 v = sys_ld128(flagsS + lane * 4);
        m = umin2(umin2(v.x, v.y), umin2(v.z, v.w));
      } else if (lane < 16) {
        uint4 v = dev_ld128(flagsD + (lane - 8) * 4);
        m = umin2(umin2(v.x, v.y), umin2(v.z, v.w));
      }
      m = umax2(m, __shfl_xor(m, 8));  // per-quad: satisfied via EITHER copy
      m = umin2(m, __shfl_xor(m, 1));
      m = umin2(m, __shfl_xor(m, 2));
      m = umin2(m, __shfl_xor(m, 4));
      if (__shfl(m, 0) >= target) break;
      __builtin_amdgcn_s_sleep(2);
    }
  }
  __syncthreads();
}

struct KP {
  const float *x, *bih0, *bhh0, *bih1, *bhh1, *Wfc, *bfc;
  float* out;
  char* ws;
};

#define MFMA(A, B, C) __builtin_amdgcn_mfma_f32_16x16x32_bf16((A), (B), (C), 0, 0, 0)

__global__ __launch_bounds__(NTHR, 1) void gru_main(KP P) {
  __shared__ f32x4 red[4][8][64];  // 32 KB cross-wave reduce (single pass)
  const int tid = threadIdx.x;
  const int lane = tid & 63;
  const int w = tid >> 6;        // K-quarter (ksteps == w mod 4)
  const int b = blockIdx.x;
  const int bg = b & 7;          // cluster: 8 batch groups x 16 rows; b%8 -> XCD if round-robin
  const int q = b >> 3;          // 0..31 within cluster
  const int layer = q & 1;
  const int colWG = q >> 1;      // 16 col groups x 32 cols

  char* ws = P.ws;
  u16* h0 = (u16*)(ws + H0_OFF);
  u16* h1 = (u16*)(ws + H1_OFF);
  u32* flagsS = (u32*)(ws + FLG_OFF) + bg * 64;  // system-scope copy (32 used)
  u32* xslot = (u32*)(ws + XSL_OFF) + bg * 64;   // slots 0..31: xcc publish
  u32* flagsD = xslot + 32;                      // device-scope copy (slots 32..63)
  const bf16x8* px = (const bf16x8*)(ws + (layer ? PX1_OFF : PX0_OFF));
  const bf16x8* ph = (const bf16x8*)(ws + (layer ? PH1_OFF : PH0_OFF));

  const float* bih = layer ? P.bih1 : P.bih0;
  const float* bhh = layer ? P.bhh1 : P.bhh0;
  const int cw = w & 1;  // col-slice owned in gate phase (waves 0,1)
  const int jcol = colWG * 32 + cw * 16 + (lane & 15);
  const float b_r = bih[jcol] + bhh[jcol];
  const float b_z = bih[HDIM + jcol] + bhh[HDIM + jcol];
  const float b_nx = bih[2 * HDIM + jcol];
  const float b_nh = bhh[2 * HDIM + jcol];

  u16* hout = layer ? h1 : h0;
  const size_t bgoff = (size_t)bg * 16 * HDIM;

  // ---- persistent B fragments: col-slices sl = colWG*2 + cs; kstep = j*4 + w ----
  bf16x8 xB[3][2][4], hB[3][2][4];
#pragma unroll
  for (int ct = 0; ct < 3; ++ct)
#pragma unroll
    for (int cs = 0; cs < 2; ++cs)
#pragma unroll
      for (int j = 0; j < 4; ++j)
        hB[ct][cs][j] =
            ph[((size_t)((colWG * 2 + cs) * 3 + ct) * 16 + (j * 4 + w)) * 64 + lane];
  if (layer == 0) {
    const bf16x8 z8 = {0, 0, 0, 0, 0, 0, 0, 0};
#pragma unroll
    for (int ct = 0; ct < 3; ++ct)
#pragma unroll
      for (int cs = 0; cs < 2; ++cs)
#pragma unroll
        for (int j = 0; j < 4; ++j) xB[ct][cs][j] = z8;
    if (w < 2) {
#pragma unroll
      for (int ct = 0; ct < 3; ++ct)
#pragma unroll
        for (int cs = 0; cs < 2; ++cs)
          xB[ct][cs][0] = px[((size_t)((colWG * 2 + cs) * 3 + ct) * 2 + w) * 64 + lane];
    }
  } else {
#pragma unroll
    for (int ct = 0; ct < 3; ++ct)
#pragma unroll
      for (int cs = 0; cs < 2; ++cs)
#pragma unroll
        for (int j = 0; j < 4; ++j)
          xB[ct][cs][j] =
              px[((size_t)((colWG * 2 + cs) * 3 + ct) * 16 + (j * 4 + w)) * 64 + lane];
  }

  // ---- phase A: publish XCC_ID, verify cluster is XCD-local (G16-safe) ----
  u32 xcc = 0;
  asm volatile("s_getreg_b32 %0, hwreg(HW_REG_XCC_ID)" : "=s"(xcc));
  if (tid == 0) sys_st32(xslot + q, xcc + 1u);
  fast_barrier(flagsS, flagsD, q, 1u);
  u32 mn = 0xFFFFFFFFu, mx = 0u;
  if (lane < 8) {
    uint4 v = sys_ld128(xslot + lane * 4);
    mn = umin2(umin2(v.x, v.y), umin2(v.z, v.w));
    mx = umax2(umax2(v.x, v.y), umax2(v.z, v.w));
  }
  mn = umin2(mn, __shfl_xor(mn, 1)); mx = umax2(mx, __shfl_xor(mx, 1));
  mn = umin2(mn, __shfl_xor(mn, 2)); mx = umax2(mx, __shfl_xor(mx, 2));
  mn = umin2(mn, __shfl_xor(mn, 4)); mx = umax2(mx, __shfl_xor(mx, 4));
  mn = __shfl(mn, 0); mx = __shfl(mx, 0);
  const bool isLocal = (mn != 0u) && (mn == mx);

  const f32x4 zf = {0.f, 0.f, 0.f, 0.f};
  f32x4 hown = zf;

#pragma unroll 1
  for (int tick = 0; tick <= TLEN; ++tick) {
    const int p = tick & 1;
    const bool active = (layer == 0) ? (tick < TLEN) : (tick >= 1);
    if (active) {
      f32x4 aR[2], aZ[2], aXN[2], aHN[2];
#pragma unroll
      for (int cs = 0; cs < 2; ++cs) { aR[cs] = zf; aZ[cs] = zf; aXN[cs] = zf; aHN[cs] = zf; }
      const u16* h0src = h0 + (size_t)(1 - p) * BATCH * HDIM + bgoff;

      if (layer == 0) {
        if (w < 2) {  // x-gemm (K=64), cached fp32 x
          const float* s = P.x +
              ((size_t)(bg * 16 + (lane & 15)) * TLEN + tick) * IDIM +
              w * 32 + ((lane >> 4) * 8);
          float4 v0 = ((const float4*)s)[0];
          float4 v1 = ((const float4*)s)[1];
          bf16x8 A;
          A[0] = (short)f2bf(v0.x); A[1] = (short)f2bf(v0.y);
          A[2] = (short)f2bf(v0.z); A[3] = (short)f2bf(v0.w);
          A[4] = (short)f2bf(v1.x); A[5] = (short)f2bf(v1.y);
          A[6] = (short)f2bf(v1.z); A[7] = (short)f2bf(v1.w);
#pragma unroll
          for (int cs = 0; cs < 2; ++cs) {
            aR[cs] = MFMA(A, xB[0][cs][0], aR[cs]);
            aZ[cs] = MFMA(A, xB[1][cs][0], aZ[cs]);
            aXN[cs] = MFMA(A, xB[2][cs][0], aXN[cs]);
          }
        }
        bf16x8 A[4];
        if (isLocal) {
#pragma unroll
          for (int j = 0; j < 4; ++j)
            l2_ldA(A[j], h0src + (size_t)(lane & 15) * HDIM + (j * 4 + w) * 32 +
                             ((lane >> 4) * 8));
        } else {
#pragma unroll
          for (int j = 0; j < 4; ++j)
            sys_ldA(A[j], h0src + (size_t)(lane & 15) * HDIM + (j * 4 + w) * 32 +
                              ((lane >> 4) * 8));
        }
        asm volatile("s_waitcnt vmcnt(0)" ::: "memory");
        __builtin_amdgcn_sched_barrier(0);
#pragma unroll
        for (int j = 0; j < 4; ++j)
#pragma unroll
          for (int cs = 0; cs < 2; ++cs) {
            aR[cs] = MFMA(A[j], hB[0][cs][j], aR[cs]);
            aZ[cs] = MFMA(A[j], hB[1][cs][j], aZ[cs]);
            aHN[cs] = MFMA(A[j], hB[2][cs][j], aHN[cs]);
          }
      } else {
        const u16* h1src = h1 + (size_t)(1 - p) * BATCH * HDIM + bgoff;
        bf16x8 A1[4], A2[4];
        if (isLocal) {
#pragma unroll
          for (int j = 0; j < 4; ++j) {
            const size_t off = (size_t)(lane & 15) * HDIM + (j * 4 + w) * 32 +
                               ((lane >> 4) * 8);
            l2_ldA(A1[j], h0src + off);
            l2_ldA(A2[j], h1src + off);
          }
        } else {
#pragma unroll
          for (int j = 0; j < 4; ++j) {
            const size_t off = (size_t)(lane & 15) * HDIM + (j * 4 + w) * 32 +
                               ((lane >> 4) * 8);
            sys_ldA(A1[j], h0src + off);
            sys_ldA(A2[j], h1src + off);
          }
        }
        asm volatile("s_waitcnt vmcnt(0)" ::: "memory");
        __builtin_amdgcn_sched_barrier(0);
#pragma unroll
        for (int j = 0; j < 4; ++j)
#pragma unroll
          for (int cs = 0; cs < 2; ++cs) {
            aR[cs] = MFMA(A1[j], xB[0][cs][j], aR[cs]);
            aZ[cs] = MFMA(A1[j], xB[1][cs][j], aZ[cs]);
            aXN[cs] = MFMA(A1[j], xB[2][cs][j], aXN[cs]);
          }
#pragma unroll
        for (int j = 0; j < 4; ++j)
#pragma unroll
          for (int cs = 0; cs < 2; ++cs) {
            aR[cs] = MFMA(A2[j], hB[0][cs][j], aR[cs]);
            aZ[cs] = MFMA(A2[j], hB[1][cs][j], aZ[cs]);
            aHN[cs] = MFMA(A2[j], hB[2][cs][j], aHN[cs]);
          }
      }

      // ---- cross-wave K reduction, single pass (fenced by barrier syncthreads) ----
#pragma unroll
      for (int cs = 0; cs < 2; ++cs) {
        red[w][0 + cs][lane] = aR[cs];
        red[w][2 + cs][lane] = aZ[cs];
        red[w][4 + cs][lane] = aXN[cs];
        red[w][6 + cs][lane] = aHN[cs];
      }
      __syncthreads();
      f32x4 R = zf, Z = zf, XN = zf, HN = zf;
#pragma unroll
      for (int kq = 0; kq < 4; ++kq) {
        R = R + red[kq][0 + cw][lane];
        Z = Z + red[kq][2 + cw][lane];
        XN = XN + red[kq][4 + cw][lane];
        HN = HN + red[kq][6 + cw][lane];
      }

      // ---- gates + state update + scoped h store (waves 0,1 own cs=0,1) ----
      if (w < 2) {
        u16* hw = hout + (size_t)p * BATCH * HDIM;
        u32 hv16[4];
        int rowb[4];
#pragma unroll
        for (int qq = 0; qq < 4; ++qq) {
          float r = sigm(R[qq] + b_r);
          float z = sigm(Z[qq] + b_z);
          float n = tanhfast(XN[qq] + b_nx + r * (HN[qq] + b_nh));
          float hv = (1.f - z) * n + z * hown[qq];
          hown[qq] = hv;
          hv16[qq] = (u32)f2bf(hv);
          rowb[qq] = bg * 16 + (lane >> 4) * 4 + qq;
        }
        if (isLocal) {
#pragma unroll
          for (int qq = 0; qq < 4; ++qq)
            l2_st16(&hw[(size_t)rowb[qq] * HDIM + jcol], hv16[qq]);
        } else {
#pragma unroll
          for (int qq = 0; qq < 4; ++qq)
            sys_st16(&hw[(size_t)rowb[qq] * HDIM + jcol], hv16[qq]);
        }
      }
    }
    fast_barrier(flagsS, flagsD, q, (u32)(tick + 2));
  }

  // ---- final FC + sigmoid: hT1 = h1[parity 0] ----
  if (layer == 1 && colWG == 0) {
    const u16* hT = h1;  // p=0 holds t=999
    int row = tid >> 4, qq = tid & 15;
    const u16* hr = hT + (size_t)(bg * 16 + row) * HDIM + qq * 32;
    bf16x8 hv[4];
    if (isLocal) {
#pragma unroll
      for (int c = 0; c < 4; ++c) l2_ldA(hv[c], hr + c * 8);
    } else {
#pragma unroll
      for (int c = 0; c < 4; ++c) sys_ldA(hv[c], hr + c * 8);
    }
    asm volatile("s_waitcnt vmcnt(0)" ::: "memory");
    const float* wf = P.Wfc + qq * 32;
    float s = 0.f;
#pragma unroll
    for (int c = 0; c < 4; ++c)
#pragma unroll
      for (int k = 0; k < 8; ++k) s += bf2f((u16)hv[c][k]) * wf[c * 8 + k];
    s += __shfl_xor(s, 1);
    s += __shfl_xor(s, 2);
    s += __shfl_xor(s, 4);
    s += __shfl_xor(s, 8);
    if (qq == 0) P.out[bg * 16 + row] = sigm(s + P.bfc[0]);
  }
}

extern "C" void kernel_launch(void* const* d_in, const int* in_sizes, int n_in,
                              void* d_out, int out_size, void* d_ws, size_t ws_size,
                              hipStream_t stream) {
  const float* x = (const float*)d_in[0];
  const float* Wih0 = (const float*)d_in[1];
  const float* Whh0 = (const float*)d_in[2];
  const float* bih0 = (const float*)d_in[3];
  const float* bhh0 = (const float*)d_in[4];
  const float* Wih1 = (const float*)d_in[5];
  const float* Whh1 = (const float*)d_in[6];
  const float* bih1 = (const float*)d_in[7];
  const float* bhh1 = (const float*)d_in[8];
  const float* Wfc = (const float*)d_in[9];
  const float* bfc = (const float*)d_in[10];

  hipMemsetAsync(d_ws, 0, 524288, stream);                     // h double-buffers
  hipMemsetAsync((char*)d_ws + FLG_OFF, 0, 4096, stream);      // flagsS + xslot/flagsD
  pack_weights<<<dim3(1200), dim3(NTHR), 0, stream>>>(Wih0, Whh0, Wih1, Whh1, (char*)d_ws);

  KP P = {x, bih0, bhh0, bih1, bhh1, Wfc, bfc, (float*)d_out, (char*)d_ws};
  void* args[] = {&P};
  hipError_t ce = hipLaunchCooperativeKernel((void*)gru_main, dim3(NWG), dim3(NTHR), args, 0,
                                             stream);
  if (ce != hipSuccess) {
    // 256 WGs x 4 waves: 1 wave/SIMD minimum -> always fully co-resident on 256 CUs;
    // barrier is hand-rolled flags, so a plain launch is safe.
    (void)hipGetLastError();  // clear error state
    gru_main<<<dim3(NWG), dim3(NTHR), 0, stream>>>(P);
  }
}

// Round 14
// 3876.159 us; speedup vs baseline: 1.0399x; 1.0399x over previous
//
#include <hip/hip_runtime.h>

typedef unsigned int u32;
typedef unsigned short u16;
typedef short bf16x8 __attribute__((ext_vector_type(8)));
typedef float f32x4 __attribute__((ext_vector_type(4)));

#define TLEN 1000
#define BATCH 128
#define IDIM 64
#define HDIM 512

#define NWG 256
#define NTHR 256

// ws byte offsets: h0/h1 are 4-deep (slot = tick & 3)
#define H0_OFF 0
#define H1_OFF 524288
#define PX0_OFF 1048576
#define PH0_OFF 1245184
#define PX1_OFF 2818048
#define PH1_OFF 4390912
#define FLG_OFF 5963776
#define XSL_OFF 5967872

__device__ __forceinline__ u16 f2bf(float f) {
  u32 u = __float_as_uint(f);
  u += 0x7fffu + ((u >> 16) & 1u);
  return (u16)(u >> 16);
}
__device__ __forceinline__ float bf2f(u16 h) { return __uint_as_float(((u32)h) << 16); }
__device__ __forceinline__ float sigm(float x) { return 1.0f / (1.0f + __expf(-x)); }
__device__ __forceinline__ float tanhfast(float x) {
  float e = __expf(-2.0f * fabsf(x));
  float t = (1.0f - e) / (1.0f + e);
  return x >= 0.0f ? t : -t;
}
__device__ __forceinline__ u32 umin2(u32 a, u32 b) { return a < b ? a : b; }
__device__ __forceinline__ u32 umax2(u32 a, u32 b) { return a > b ? a : b; }

// ---- system scope (sc0 sc1): proven r6-r13 ----
__device__ __forceinline__ void sys_st16(u16* p, u32 v) {
  asm volatile("global_store_short %0, %1, off sc0 sc1" ::"v"(p), "v"(v) : "memory");
}
__device__ __forceinline__ void sys_st32(u32* p, u32 v) {
  asm volatile("global_store_dword %0, %1, off sc0 sc1" ::"v"(p), "v"(v) : "memory");
}
__device__ __forceinline__ uint4 sys_ld128(const u32* p) {
  uint4 v;
  asm volatile("global_load_dwordx4 %0, %1, off sc0 sc1\n\ts_waitcnt vmcnt(0)"
               : "=v"(v) : "v"(p) : "memory");
  return v;
}
__device__ __forceinline__ void sys_ldA(bf16x8& d, const u16* p) {
  asm volatile("global_load_dwordx4 %0, %1, off sc0 sc1" : "=v"(d) : "v"(p));
}
// ---- sc0 ops: XCD-L2 coherent for DATA (proven r11/r13). For flags: used only
//      as the FAST copy of a dual-scope scheme (sys copy guarantees progress).
__device__ __forceinline__ void l2_st16(u16* p, u32 v) {
  asm volatile("global_store_short %0, %1, off sc0" ::"v"(p), "v"(v) : "memory");
}
__device__ __forceinline__ void l2_st32(u32* p, u32 v) {
  asm volatile("global_store_dword %0, %1, off sc0" ::"v"(p), "v"(v) : "memory");
}
__device__ __forceinline__ uint4 l2_ld128(const u32* p) {
  uint4 v;
  asm volatile("global_load_dwordx4 %0, %1, off sc0\n\ts_waitcnt vmcnt(0)"
               : "=v"(v) : "v"(p) : "memory");
  return v;
}
__device__ __forceinline__ void l2_ldA(bf16x8& d, const u16* p) {
  asm volatile("global_load_dwordx4 %0, %1, off sc0" : "=v"(d) : "v"(p));
}

// ---------------- weight pre-pack into MFMA B-fragment order (unchanged) ------
__global__ void pack_weights(const float* Wih0, const float* Whh0,
                             const float* Wih1, const float* Whh1, char* ws) {
  int fid = blockIdx.x * NTHR + threadIdx.x;
  const float* src;
  int K, Kks;
  size_t obase;
  int f = fid;
  if (f < 12288) {
    src = Wih0; K = 64; Kks = 2; obase = PX0_OFF;
  } else if (f < 12288 + 98304) {
    f -= 12288; src = Whh0; K = 512; Kks = 16; obase = PH0_OFF;
  } else if (f < 12288 + 2 * 98304) {
    f -= 12288 + 98304; src = Wih1; K = 512; Kks = 16; obase = PX1_OFF;
  } else if (f < 12288 + 3 * 98304) {
    f -= 12288 + 2 * 98304; src = Whh1; K = 512; Kks = 16; obase = PH1_OFF;
  } else {
    return;
  }
  int lane = f & 63;
  int r = f >> 6;
  int ks = r % Kks; r /= Kks;
  int ct = r % 3;
  int sl = r / 3;
  int grow = ct * 512 + sl * 16 + (lane & 15);
  int k = ks * 32 + ((lane >> 4) * 8);
  const float* s = src + (size_t)grow * K + k;
  u32 p0 = f2bf(s[0]) | ((u32)f2bf(s[1]) << 16);
  u32 p1 = f2bf(s[2]) | ((u32)f2bf(s[3]) << 16);
  u32 p2 = f2bf(s[4]) | ((u32)f2bf(s[5]) << 16);
  u32 p3 = f2bf(s[6]) | ((u32)f2bf(s[7]) << 16);
  *(uint4*)(ws + obase + (size_t)f * 16) = make_uint4(p0, p1, p2, p3);
}

struct KP {
  const float *x, *bih0, *bhh0, *bih1, *bhh1, *Wfc, *bfc;
  float* out;
  char* ws;
};

#define MFMA(A, B, C) __builtin_amdgcn_mfma_f32_16x16x32_bf16((A), (B), (C), 0, 0, 0)

// relaxed wait: min( minL0, minL1 + bias ) >= k, where each flag is the max of
// its sys and fast (sc0) views. fl* are 16-u32 arrays.
__device__ __forceinline__ void wait_flags(const u32* fl0s, const u32* fl1s,
                                           const u32* fl0f, const u32* fl1f,
                                           u32 bias, u32 k) {
  if (threadIdx.x < 64) {
    const int lane = threadIdx.x;
    for (;;) {
      u32 m = 0xFFFFFFFFu;
      if (lane < 4) {
        uint4 v = sys_ld128(fl0s + lane * 4);
        m = umin2(umin2(v.x, v.y), umin2(v.z, v.w));
      } else if (lane < 8) {
        uint4 v = sys_ld128(fl1s + (lane - 4) * 4);
        m = umin2(umin2(v.x, v.y), umin2(v.z, v.w)) + bias;
      } else if (lane < 12) {
        uint4 v = l2_ld128(fl0f + (lane - 8) * 4);
        m = umin2(umin2(v.x, v.y), umin2(v.z, v.w));
      } else if (lane < 16) {
        uint4 v = l2_ld128(fl1f + (lane - 12) * 4);
        m = umin2(umin2(v.x, v.y), umin2(v.z, v.w)) + bias;
      }
      m = umax2(m, __shfl_xor(m, 8));  // per-flag-group: best of sys/fast views
      m = umin2(m, __shfl_xor(m, 4));
      m = umin2(m, __shfl_xor(m, 2));
      m = umin2(m, __shfl_xor(m, 1));
      if (__shfl(m, 0) >= k) break;
      __builtin_amdgcn_s_sleep(1);
    }
  }
  __syncthreads();
}

__global__ __launch_bounds__(NTHR, 1) void gru_main(KP P) {
  __shared__ f32x4 red[4][8][64];  // 32 KB cross-wave reduce (single pass)
  const int tid = threadIdx.x;
  const int lane = tid & 63;
  const int w = tid >> 6;        // K-quarter (ksteps == w mod 4)
  const int b = blockIdx.x;
  const int bg = b & 7;          // cluster: 8 batch groups x 16 rows; b%8 -> XCD round-robin
  const int q = b >> 3;          // 0..31 within cluster
  const int layer = q & 1;
  const int colWG = q >> 1;      // 16 col groups x 32 cols

  char* ws = P.ws;
  u16* h0 = (u16*)(ws + H0_OFF);
  u16* h1 = (u16*)(ws + H1_OFF);
  u32* fb = (u32*)(ws + FLG_OFF) + bg * 128;  // 512B/cluster
  u32* fl0s = fb;          // L0 flags, sys copy (16 u32)
  u32* fl1s = fb + 32;     // L1 flags, sys copy
  u32* fl0f = fb + 64;     // L0 flags, fast (sc0) copy
  u32* fl1f = fb + 96;     // L1 flags, fast copy
  u32* xsl = (u32*)(ws + XSL_OFF) + bg * 64;  // 0..31 xcc, 32..63 phase-A flags
  u32* phf = xsl + 32;
  const bf16x8* px = (const bf16x8*)(ws + (layer ? PX1_OFF : PX0_OFF));
  const bf16x8* ph = (const bf16x8*)(ws + (layer ? PH1_OFF : PH0_OFF));

  u32* mySig_s = (layer ? fl1s : fl0s) + colWG;
  u32* mySig_f = (layer ? fl1f : fl0f) + colWG;

  const float* bih = layer ? P.bih1 : P.bih0;
  const float* bhh = layer ? P.bhh1 : P.bhh0;
  const int cw = w & 1;  // col-slice owned in gate phase (waves 0,1)
  const int jcol = colWG * 32 + cw * 16 + (lane & 15);
  const float b_r = bih[jcol] + bhh[jcol];
  const float b_z = bih[HDIM + jcol] + bhh[HDIM + jcol];
  const float b_nx = bih[2 * HDIM + jcol];
  const float b_nh = bhh[2 * HDIM + jcol];

  const size_t bgoff = (size_t)bg * 16 * HDIM;
  const size_t SLOT = (size_t)BATCH * HDIM;

  // ---- persistent B fragments: col-slices sl = colWG*2 + cs; kstep = j*4 + w ----
  bf16x8 xB[3][2][4], hB[3][2][4];
#pragma unroll
  for (int ct = 0; ct < 3; ++ct)
#pragma unroll
    for (int cs = 0; cs < 2; ++cs)
#pragma unroll
      for (int j = 0; j < 4; ++j)
        hB[ct][cs][j] =
            ph[((size_t)((colWG * 2 + cs) * 3 + ct) * 16 + (j * 4 + w)) * 64 + lane];
  if (layer == 0) {
    const bf16x8 z8 = {0, 0, 0, 0, 0, 0, 0, 0};
#pragma unroll
    for (int ct = 0; ct < 3; ++ct)
#pragma unroll
      for (int cs = 0; cs < 2; ++cs)
#pragma unroll
        for (int j = 0; j < 4; ++j) xB[ct][cs][j] = z8;
    if (w < 2) {
#pragma unroll
      for (int ct = 0; ct < 3; ++ct)
#pragma unroll
        for (int cs = 0; cs < 2; ++cs)
          xB[ct][cs][0] = px[((size_t)((colWG * 2 + cs) * 3 + ct) * 2 + w) * 64 + lane];
    }
  } else {
#pragma unroll
    for (int ct = 0; ct < 3; ++ct)
#pragma unroll
      for (int cs = 0; cs < 2; ++cs)
#pragma unroll
        for (int j = 0; j < 4; ++j)
          xB[ct][cs][j] =
              px[((size_t)((colWG * 2 + cs) * 3 + ct) * 16 + (j * 4 + w)) * 64 + lane];
  }

  // ---- phase A: publish XCC_ID, one full-cluster sys barrier, verdict ----
  u32 xcc = 0;
  asm volatile("s_getreg_b32 %0, hwreg(HW_REG_XCC_ID)" : "=s"(xcc));
  if (tid == 0) sys_st32(xsl + q, xcc + 1u);
  __syncthreads();
  if (tid == 0) sys_st32(phf + q, 1u);
  if (tid < 64) {
    for (;;) {
      u32 m = 0xFFFFFFFFu;
      if (lane < 8) {
        uint4 v = sys_ld128(phf + lane * 4);
        m = umin2(umin2(v.x, v.y), umin2(v.z, v.w));
      }
      m = umin2(m, __shfl_xor(m, 1));
      m = umin2(m, __shfl_xor(m, 2));
      m = umin2(m, __shfl_xor(m, 4));
      if (__shfl(m, 0) >= 1u) break;
      __builtin_amdgcn_s_sleep(2);
    }
  }
  __syncthreads();
  u32 mn = 0xFFFFFFFFu, mx = 0u;
  if (lane < 8) {
    uint4 v = sys_ld128(xsl + lane * 4);
    mn = umin2(umin2(v.x, v.y), umin2(v.z, v.w));
    mx = umax2(umax2(v.x, v.y), umax2(v.z, v.w));
  }
  mn = umin2(mn, __shfl_xor(mn, 1)); mx = umax2(mx, __shfl_xor(mx, 1));
  mn = umin2(mn, __shfl_xor(mn, 2)); mx = umax2(mx, __shfl_xor(mx, 2));
  mn = umin2(mn, __shfl_xor(mn, 4)); mx = umax2(mx, __shfl_xor(mx, 4));
  mn = __shfl(mn, 0); mx = __shfl(mx, 0);
  const bool isLocal = (mn != 0u) && (mn == mx);

  const f32x4 zf = {0.f, 0.f, 0.f, 0.f};
  f32x4 hown = zf;

#pragma unroll 1
  for (int k = 0; k <= TLEN; ++k) {
    const bool active = (layer == 0) ? (k < TLEN) : (k >= 1);
    if (active) {
      f32x4 aR[2], aZ[2], aXN[2], aHN[2];
#pragma unroll
      for (int cs = 0; cs < 2; ++cs) { aR[cs] = zf; aZ[cs] = zf; aXN[cs] = zf; aHN[cs] = zf; }
      const u16* h0src = h0 + (size_t)((k + 3) & 3) * SLOT + bgoff;  // h0[k-1]

      if (layer == 0) {
        // ---- x-gemm for tick k BEFORE the wait (barrier-independent) ----
        if (w < 2) {
          const float* s = P.x +
              ((size_t)(bg * 16 + (lane & 15)) * TLEN + k) * IDIM +
              w * 32 + ((lane >> 4) * 8);
          float4 v0 = ((const float4*)s)[0];
          float4 v1 = ((const float4*)s)[1];
          bf16x8 A;
          A[0] = (short)f2bf(v0.x); A[1] = (short)f2bf(v0.y);
          A[2] = (short)f2bf(v0.z); A[3] = (short)f2bf(v0.w);
          A[4] = (short)f2bf(v1.x); A[5] = (short)f2bf(v1.y);
          A[6] = (short)f2bf(v1.z); A[7] = (short)f2bf(v1.w);
#pragma unroll
          for (int cs = 0; cs < 2; ++cs) {
            aR[cs] = MFMA(A, xB[0][cs][0], aR[cs]);
            aZ[cs] = MFMA(A, xB[1][cs][0], aZ[cs]);
            aXN[cs] = MFMA(A, xB[2][cs][0], aXN[cs]);
          }
        }
        // L0 wait: minL0 >= k, minL1 >= k-2
        if (k > 0) wait_flags(fl0s, fl1s, fl0f, fl1f, 2u, (u32)k);
        bf16x8 A[4];
        if (isLocal) {
#pragma unroll
          for (int j = 0; j < 4; ++j)
            l2_ldA(A[j], h0src + (size_t)(lane & 15) * HDIM + (j * 4 + w) * 32 +
                             ((lane >> 4) * 8));
        } else {
#pragma unroll
          for (int j = 0; j < 4; ++j)
            sys_ldA(A[j], h0src + (size_t)(lane & 15) * HDIM + (j * 4 + w) * 32 +
                              ((lane >> 4) * 8));
        }
        asm volatile("s_waitcnt vmcnt(0)" ::: "memory");
        __builtin_amdgcn_sched_barrier(0);
#pragma unroll
        for (int j = 0; j < 4; ++j)
#pragma unroll
          for (int cs = 0; cs < 2; ++cs) {
            aR[cs] = MFMA(A[j], hB[0][cs][j], aR[cs]);
            aZ[cs] = MFMA(A[j], hB[1][cs][j], aZ[cs]);
            aHN[cs] = MFMA(A[j], hB[2][cs][j], aHN[cs]);
          }
      } else {
        // L1 wait: minL0 >= k, minL1 >= k-1
        wait_flags(fl0s, fl1s, fl0f, fl1f, 1u, (u32)k);
        const u16* h1src = h1 + (size_t)((k + 2) & 3) * SLOT + bgoff;  // h1[k-2]
        bf16x8 A1[4], A2[4];
        if (isLocal) {
#pragma unroll
          for (int j = 0; j < 4; ++j) {
            const size_t off = (size_t)(lane & 15) * HDIM + (j * 4 + w) * 32 +
                               ((lane >> 4) * 8);
            l2_ldA(A1[j], h0src + off);
            l2_ldA(A2[j], h1src + off);
          }
        } else {
#pragma unroll
          for (int j = 0; j < 4; ++j) {
            const size_t off = (size_t)(lane & 15) * HDIM + (j * 4 + w) * 32 +
                               ((lane >> 4) * 8);
            sys_ldA(A1[j], h0src + off);
            sys_ldA(A2[j], h1src + off);
          }
        }
        asm volatile("s_waitcnt vmcnt(0)" ::: "memory");
        __builtin_amdgcn_sched_barrier(0);
#pragma unroll
        for (int j = 0; j < 4; ++j)
#pragma unroll
          for (int cs = 0; cs < 2; ++cs) {
            aR[cs] = MFMA(A1[j], xB[0][cs][j], aR[cs]);
            aZ[cs] = MFMA(A1[j], xB[1][cs][j], aZ[cs]);
            aXN[cs] = MFMA(A1[j], xB[2][cs][j], aXN[cs]);
          }
#pragma unroll
        for (int j = 0; j < 4; ++j)
#pragma unroll
          for (int cs = 0; cs < 2; ++cs) {
            aR[cs] = MFMA(A2[j], hB[0][cs][j], aR[cs]);
            aZ[cs] = MFMA(A2[j], hB[1][cs][j], aZ[cs]);
            aHN[cs] = MFMA(A2[j], hB[2][cs][j], aHN[cs]);
          }
      }

      // ---- cross-wave K reduction, single pass ----
#pragma unroll
      for (int cs = 0; cs < 2; ++cs) {
        red[w][0 + cs][lane] = aR[cs];
        red[w][2 + cs][lane] = aZ[cs];
        red[w][4 + cs][lane] = aXN[cs];
        red[w][6 + cs][lane] = aHN[cs];
      }
      __syncthreads();
      f32x4 R = zf, Z = zf, XN = zf, HN = zf;
#pragma unroll
      for (int kq = 0; kq < 4; ++kq) {
        R = R + red[kq][0 + cw][lane];
        Z = Z + red[kq][2 + cw][lane];
        XN = XN + red[kq][4 + cw][lane];
        HN = HN + red[kq][6 + cw][lane];
      }
      __syncthreads();  // red reusable next iter; also pre-signal rendezvous

      // ---- gates + state update + scoped h store (waves 0,1 own cs=0,1) ----
      if (w < 2) {
        // L0 writes h0[k] -> slot k&3 ; L1 writes h1[k-1] -> slot (k+3)&3
        u16* hw = (layer ? h1 + (size_t)((k + 3) & 3) * SLOT
                         : h0 + (size_t)(k & 3) * SLOT);
        u32 hv16[4];
        int rowb[4];
#pragma unroll
        for (int qq = 0; qq < 4; ++qq) {
          float r = sigm(R[qq] + b_r);
          float z = sigm(Z[qq] + b_z);
          float n = tanhfast(XN[qq] + b_nx + r * (HN[qq] + b_nh));
          float hv = (1.f - z) * n + z * hown[qq];
          hown[qq] = hv;
          hv16[qq] = (u32)f2bf(hv);
          rowb[qq] = bg * 16 + (lane >> 4) * 4 + qq;
        }
        if (isLocal) {
#pragma unroll
          for (int qq = 0; qq < 4; ++qq)
            l2_st16(&hw[(size_t)rowb[qq] * HDIM + jcol], hv16[qq]);
        } else {
#pragma unroll
          for (int qq = 0; qq < 4; ++qq)
            sys_st16(&hw[(size_t)rowb[qq] * HDIM + jcol], hv16[qq]);
        }
      }

      // ---- signal iteration k complete (flag = k+1), dual scope ----
      __syncthreads();  // all waves' h stores drained (compiler vmcnt before barrier)
      if (tid == 0) {
        asm volatile("s_waitcnt vmcnt(0)" ::: "memory");
        l2_st32(mySig_f, (u32)(k + 1));
        sys_st32(mySig_s, (u32)(k + 1));
      }
    }
  }

  // ---- final FC + sigmoid: needs all L1 flags >= TLEN+1; h1[999] = slot 3 ----
  if (layer == 1 && colWG == 0) {
    if (tid < 64) {
      for (;;) {
        u32 m = 0xFFFFFFFFu;
        if (lane < 4) {
          uint4 v = sys_ld128(fl1s + lane * 4);
          m = umin2(umin2(v.x, v.y), umin2(v.z, v.w));
        } else if (lane < 8) {
          uint4 v = l2_ld128(fl1f + (lane - 4) * 4);
          m = umin2(umin2(v.x, v.y), umin2(v.z, v.w));
        }
        m = umax2(m, __shfl_xor(m, 4));
        m = umin2(m, __shfl_xor(m, 1));
        m = umin2(m, __shfl_xor(m, 2));
        if (__shfl(m, 0) >= (u32)(TLEN + 1)) break;
        __builtin_amdgcn_s_sleep(1);
      }
    }
    __syncthreads();
    const u16* hT = h1 + (size_t)((TLEN + 3) & 3) * SLOT;
    int row = tid >> 4, qq = tid & 15;
    const u16* hr = hT + (size_t)(bg * 16 + row) * HDIM + qq * 32;
    bf16x8 hv[4];
    if (isLocal) {
#pragma unroll
      for (int c = 0; c < 4; ++c) l2_ldA(hv[c], hr + c * 8);
    } else {
#pragma unroll
      for (int c = 0; c < 4; ++c) sys_ldA(hv[c], hr + c * 8);
    }
    asm volatile("s_waitcnt vmcnt(0)" ::: "memory");
    const float* wf = P.Wfc + qq * 32;
    float s = 0.f;
#pragma unroll
    for (int c = 0; c < 4; ++c)
#pragma unroll
      for (int k2 = 0; k2 < 8; ++k2) s += bf2f((u16)hv[c][k2]) * wf[c * 8 + k2];
    s += __shfl_xor(s, 1);
    s += __shfl_xor(s, 2);
    s += __shfl_xor(s, 4);
    s += __shfl_xor(s, 8);
    if (qq == 0) P.out[bg * 16 + row] = sigm(s + P.bfc[0]);
  }
}

extern "C" void kernel_launch(void* const* d_in, const int* in_sizes, int n_in,
                              void* d_out, int out_size, void* d_ws, size_t ws_size,
                              hipStream_t stream) {
  const float* x = (const float*)d_in[0];
  const float* Wih0 = (const float*)d_in[1];
  const float* Whh0 = (const float*)d_in[2];
  const float* bih0 = (const float*)d_in[3];
  const float* bhh0 = (const float*)d_in[4];
  const float* Wih1 = (const float*)d_in[5];
  const float* Whh1 = (const float*)d_in[6];
  const float* bih1 = (const float*)d_in[7];
  const float* bhh1 = (const float*)d_in[8];
  const float* Wfc = (const float*)d_in[9];
  const float* bfc = (const float*)d_in[10];

  hipMemsetAsync(d_ws, 0, 1048576, stream);                      // h0/h1 x 4 slots
  hipMemsetAsync((char*)d_ws + FLG_OFF, 0, 6144, stream);        // flags + xcc/phaseA
  pack_weights<<<dim3(1200), dim3(NTHR), 0, stream>>>(Wih0, Whh0, Wih1, Whh1, (char*)d_ws);

  KP P = {x, bih0, bhh0, bih1, bhh1, Wfc, bfc, (float*)d_out, (char*)d_ws};
  void* args[] = {&P};
  hipError_t ce = hipLaunchCooperativeKernel((void*)gru_main, dim3(NWG), dim3(NTHR), args, 0,
                                             stream);
  if (ce != hipSuccess) {
    // 256 WGs x 4 waves: 1 wave/SIMD minimum -> always fully co-resident on 256 CUs;
    // sync is hand-rolled monotonic flags, so a plain launch is safe.
    (void)hipGetLastError();  // clear error state
    gru_main<<<dim3(NWG), dim3(NTHR), 0, stream>>>(P);
  }
}